// Round 13
// baseline (124.402 us; speedup 1.0000x reference)
//
#include <hip/hip_runtime.h>

#define HW   4096
#define CIN  32
// scale in log2 domain: (1/sqrt(NCLASS)) * log2(e); NCLASS = 2
#define SCALE2 (0.70710678118654752f * 1.44269504088896340f)

// Raw v_exp_f32 (2^x): args bounded (|x| <~ 12), skip libm denormal fixup.
__device__ __forceinline__ float exp2_raw(float x) {
#if __has_builtin(__builtin_amdgcn_exp2f)
    return __builtin_amdgcn_exp2f(x);
#else
    float r;
    asm("v_exp_f32 %0, %1" : "=v"(r) : "v"(x));
    return r;
#endif
}

// Single dispatch. 1024 blocks x 256 thr, 4 blocks/CU exactly -> all co-resident
// at t=0 (grid == capacity; every block lands in a free slot immediately).
// Block b owns 16 columns: n = b>>8, pg = (b&255)*16 (same cols for p-role and q-role).
//   P (b<256):  f2 projection for 64 columns -> f2v; release-add ctr[batch].
//   prep:       f1 (scaled) + g = f2 of our 16 cols recomputed from feat (no dep).
//   spin-1:     RELAXED poll ctr[n]==64, then ONE agent-acquire fence (L2 inv).
//   B:          l[p] over all q (round-10 loop) -> stats4; release-add ctr2[batch].
//   spin-2:     RELAXED poll ctr2[n]==256, one acquire fence.
//   C:          o[c,q] over all p (round-10 loop) -> out.
__global__ __launch_bounds__(256, 4) void corr_fused(
        const float* __restrict__ feat, const float* __restrict__ outv,
        const float* __restrict__ w1, const float* __restrict__ b1,
        const float* __restrict__ w2, const float* __restrict__ b2,
        float2* __restrict__ f2v, float4* __restrict__ stats4,
        int* __restrict__ ctr, float* __restrict__ o) {
    __shared__ float2 redP[4][64];
    __shared__ float2 sf1[16];     // scaled f1 of our 16 cols
    __shared__ float2 sg[16];      // f2 of our 16 cols
    __shared__ float  pB[4][17];
    __shared__ float  pC[4][33];

    int tid = threadIdx.x;
    int lane = tid & 63;
    int wid = tid >> 6;
    int b = blockIdx.x;
    int n = b >> 8;
    int pg = (b & 255) << 4;
    int base = n * HW;

    // ---------------- Phase P: f2v producers (blocks 0..255) ----------------
    if (b < 256) {
        int np = b >> 6;
        int col = ((b & 63) << 6) + lane;
        const float* fbase = feat + ((size_t)np * CIN + wid * 8) * HW + col;
        float a0 = 0.f, a1 = 0.f;
#pragma unroll
        for (int c = 0; c < 8; ++c) {
            float v = fbase[(size_t)c * HW];
            a0 += v * w2[wid * 8 + c];
            a1 += v * w2[32 + wid * 8 + c];
        }
        redP[wid][lane] = make_float2(a0, a1);
        __syncthreads();
        if (tid < 64) {
            float2 r0 = redP[0][tid], r1 = redP[1][tid], r2 = redP[2][tid], r3 = redP[3][tid];
            f2v[np * HW + ((b & 63) << 6) + tid] =
                make_float2(r0.x + r1.x + r2.x + r3.x + b2[0],
                            r0.y + r1.y + r2.y + r3.y + b2[1]);
        }
        __syncthreads();               // stores drained (vmcnt(0) before barrier)
        if (tid == 0)                  // release => L2 writeback, then add
            __hip_atomic_fetch_add(&ctr[np << 5], 1, __ATOMIC_RELEASE,
                                   __HIP_MEMORY_SCOPE_AGENT);
    }

    // ---- prep: f1 (scaled) and g for our 16 columns, straight from feat ----
    if (tid < 32) {
        int pl = tid & 15, ch = tid >> 4;
        const float* fp = feat + (size_t)n * CIN * HW + pg + pl;
        const float* wr = w1 + ch * CIN;
        float s = 0.f;
#pragma unroll 8
        for (int c = 0; c < CIN; ++c) s += fp[(size_t)c * HW] * wr[c];
        ((float*)&sf1[pl])[ch] = (s + b1[ch]) * SCALE2;
    } else if (tid < 64) {
        int ql = tid & 15, ch = (tid >> 4) & 1;
        const float* fp = feat + (size_t)n * CIN * HW + pg + ql;
        const float* wr = w2 + ch * CIN;
        float s = 0.f;
#pragma unroll 8
        for (int c = 0; c < CIN; ++c) s += fp[(size_t)c * HW] * wr[c];
        ((float*)&sg[ql])[ch] = s + b2[ch];
    }

    // ---- spin-1: relaxed poll (no per-poll invalidate), one acquire fence ----
    if (tid == 0) {
        while (__hip_atomic_load(&ctr[n << 5], __ATOMIC_RELAXED,
                                 __HIP_MEMORY_SCOPE_AGENT) < 64)
            __builtin_amdgcn_s_sleep(16);
    }
    __syncthreads();
    __builtin_amdgcn_fence(__ATOMIC_ACQUIRE, "agent");

    // ---------------- Phase B: l[p] for our 16 p's (round-10 loop) ----------------
    {
        float f10[16], f11[16];
#pragma unroll
        for (int j = 0; j < 16; ++j) { float2 t = sf1[j]; f10[j] = t.x; f11[j] = t.y; }
        const float4* f2b = (const float4*)(f2v + base) + wid * 512 + lane;
        float v[16];
#pragma unroll
        for (int j = 0; j < 16; ++j) v[j] = 0.f;
        float4 cur = f2b[0];
#pragma unroll
        for (int s = 0; s < 8; ++s) {
            float4 nxt = f2b[((s + 1) & 7) * 64];   // distance-1 rotation
#pragma unroll
            for (int j = 0; j < 16; ++j) {
                float e0 = exp2_raw(f10[j] * cur.x + f11[j] * cur.y);
                float e1 = exp2_raw(f10[j] * cur.z + f11[j] * cur.w);
                v[j] += e0 + e1;
            }
            cur = nxt;
        }
        // recursive-halving exchange: lane ends holding idx = lane&15
        bool up8 = lane & 8;
#pragma unroll
        for (int k = 0; k < 8; ++k) {
            float send = up8 ? v[k] : v[k + 8];
            float recv = __shfl_xor(send, 8);
            v[k] = (up8 ? v[k + 8] : v[k]) + recv;
        }
        bool up4 = lane & 4;
#pragma unroll
        for (int k = 0; k < 4; ++k) {
            float send = up4 ? v[k] : v[k + 4];
            float recv = __shfl_xor(send, 4);
            v[k] = (up4 ? v[k + 4] : v[k]) + recv;
        }
        bool up2 = lane & 2;
#pragma unroll
        for (int k = 0; k < 2; ++k) {
            float send = up2 ? v[k] : v[k + 2];
            float recv = __shfl_xor(send, 2);
            v[k] = (up2 ? v[k + 2] : v[k]) + recv;
        }
        bool up1 = lane & 1;
        {
            float send = up1 ? v[0] : v[1];
            float recv = __shfl_xor(send, 1);
            v[0] = (up1 ? v[1] : v[0]) + recv;
        }
        v[0] += __shfl_xor(v[0], 16);
        v[0] += __shfl_xor(v[0], 32);
        if (lane < 16) pB[wid][lane] = v[0];
    }
    __syncthreads();
    if (tid < 16) {
        float lt = pB[0][tid] + pB[1][tid] + pB[2][tid] + pB[3][tid];
        float inv = 1.0f / lt;
        int pp = pg + tid;
        float2 f1 = sf1[tid];          // scaled
        float v0 = outv[(n * 2 + 0) * HW + pp];
        float v1 = outv[(n * 2 + 1) * HW + pp];
        stats4[base + pp] = make_float4(f1.x, f1.y, v0 * inv, v1 * inv);
    }
    __syncthreads();                   // stats4 stores drained
    if (tid == 0)
        __hip_atomic_fetch_add(&ctr[1024 + (n << 5)], 1, __ATOMIC_RELEASE,
                               __HIP_MEMORY_SCOPE_AGENT);

    // ---- spin-2 ----
    if (tid == 0) {
        while (__hip_atomic_load(&ctr[1024 + (n << 5)], __ATOMIC_RELAXED,
                                 __HIP_MEMORY_SCOPE_AGENT) < 256)
            __builtin_amdgcn_s_sleep(32);
    }
    __syncthreads();
    __builtin_amdgcn_fence(__ATOMIC_ACQUIRE, "agent");

    // ---------------- Phase C: o[c,q] for our 16 q's (round-10 loop) ----------------
    {
        float g0[16], g1[16];
#pragma unroll
        for (int j = 0; j < 16; ++j) { float2 t = sg[j]; g0[j] = t.x; g1[j] = t.y; }
        const float4* stb = stats4 + base + wid * 1024 + lane;
        // value layout: v[j] = (ch0, q j), v[16+j] = (ch1, q j) -> idx = ch*16+q
        float v[32];
#pragma unroll
        for (int j = 0; j < 32; ++j) v[j] = 0.f;
        float4 cur = stb[0];
#pragma unroll
        for (int s = 0; s < 16; ++s) {
            float4 nxt = stb[((s + 1) & 15) * 64];  // distance-1 rotation
#pragma unroll
            for (int j = 0; j < 16; ++j) {
                float e = exp2_raw(g0[j] * cur.x + g1[j] * cur.y);
                v[j]      += cur.z * e;
                v[16 + j] += cur.w * e;
            }
            cur = nxt;
        }
        // recursive-halving exchange over 32 values: lane ends holding idx = lane&31
        bool up16 = lane & 16;
#pragma unroll
        for (int k = 0; k < 16; ++k) {
            float send = up16 ? v[k] : v[k + 16];
            float recv = __shfl_xor(send, 16);
            v[k] = (up16 ? v[k + 16] : v[k]) + recv;
        }
        bool up8 = lane & 8;
#pragma unroll
        for (int k = 0; k < 8; ++k) {
            float send = up8 ? v[k] : v[k + 8];
            float recv = __shfl_xor(send, 8);
            v[k] = (up8 ? v[k + 8] : v[k]) + recv;
        }
        bool up4 = lane & 4;
#pragma unroll
        for (int k = 0; k < 4; ++k) {
            float send = up4 ? v[k] : v[k + 4];
            float recv = __shfl_xor(send, 4);
            v[k] = (up4 ? v[k + 4] : v[k]) + recv;
        }
        bool up2 = lane & 2;
#pragma unroll
        for (int k = 0; k < 2; ++k) {
            float send = up2 ? v[k] : v[k + 2];
            float recv = __shfl_xor(send, 2);
            v[k] = (up2 ? v[k + 2] : v[k]) + recv;
        }
        bool up1 = lane & 1;
        {
            float send = up1 ? v[0] : v[1];
            float recv = __shfl_xor(send, 1);
            v[0] = (up1 ? v[1] : v[0]) + recv;
        }
        v[0] += __shfl_xor(v[0], 32);
        if (lane < 32) pC[wid][lane] = v[0];
    }
    __syncthreads();
    if (tid < 32) {
        float r = pC[0][tid] + pC[1][tid] + pC[2][tid] + pC[3][tid];
        int ch = tid >> 4, qq = tid & 15;
        o[(n * 2 + ch) * HW + pg + qq] = r;
    }
}

extern "C" void kernel_launch(void* const* d_in, const int* in_sizes, int n_in,
                              void* d_out, int out_size, void* d_ws, size_t ws_size,
                              hipStream_t stream) {
    const float* feat = (const float*)d_in[0];   // (4,32,64,64)
    const float* outv = (const float*)d_in[1];   // (4,2,64,64)
    const float* w1   = (const float*)d_in[2];   // (2,32)
    const float* b1   = (const float*)d_in[3];   // (2,)
    const float* w2   = (const float*)d_in[4];   // (2,32)
    const float* b2   = (const float*)d_in[5];   // (2,)
    float* o = (float*)d_out;                    // (4,2,64,64)

    // workspace layout:
    float*  ws     = (float*)d_ws;
    float2* f2v    = (float2*)ws;                // 16384 float2 = 128 KB
    float4* stats4 = (float4*)(ws + 32768);      // 16384 float4 = 256 KB
    int*    ctr    = (int*)(ws + 32768 + 65536); // 2 KB counters (8 used lines)

    // zero flag counters every launch (graph-capturable memset node)
    hipMemsetAsync(ctr, 0, 8192, stream);

    corr_fused<<<1024, 256, 0, stream>>>(feat, outv, w1, b1, w2, b2,
                                         f2v, stats4, ctr, o);
}